// Round 11
// baseline (5141.715 us; speedup 1.0000x reference)
//
#include <hip/hip_runtime.h>
#include <float.h>
#include <math.h>

#define KNN    5
#define FEPS   1e-6f
#define NSAMP  10
#define NB     16
#define NBINS  4096
#define GLO    -2.4f
#define GH     0.3f
#define GINVH  (1.0f/0.3f)
#define KMASK  0xFFFFE000u

// ---- workspace layout (bytes) ----
#define OFF_SCENT   0          // float4[6016]  sorted centroids (x,y,z,|C|^2)
#define OFF_CTMP    98304      // float4[6016]  unsorted centroids
#define OFF_SPH     196608     // float4[4096]  per-bin sphere (cx,cy,cz,R)
#define OFF_SIDX    262144     // u32[6016]     sorted -> original face idx
#define OFF_BSTART  286720     // u32[4097]     bin start offsets (faces)
#define OFF_FCUR    304128     // u32[4096]     face scatter cursor
#define OFF_PCUR    321536     // u32[4096]     point scatter cursor
#define OFF_FCNT    338944     // u32[4096]     face histogram   } adjacent:
#define OFF_PCNT    355328     // u32[4096]     point histogram  } one memset
#define OFF_PERM    372736     // u32[60032]    sorted -> original point idx

static __device__ __forceinline__ unsigned umn(unsigned a, unsigned b){ return __builtin_elementwise_min(a, b); }
static __device__ __forceinline__ unsigned med3u(unsigned a, unsigned b, unsigned c){
    unsigned r; asm("v_med3_u32 %0, %1, %2, %3" : "=v"(r) : "v"(a), "v"(b), "v"(c)); return r;
}
static __device__ __forceinline__ int binCoord(float x){
    int i = (int)floorf((x - GLO) * GINVH);
    return i < 0 ? 0 : (i > NB-1 ? NB-1 : i);
}
static __device__ __forceinline__ void computeP(int p, const float* __restrict__ verts,
    const int* __restrict__ faces, const float* __restrict__ uarr, const float* __restrict__ varr,
    float& px, float& py, float& pz)
{
    float uu = uarr[p], vv = varr[p];
    if (uu + vv > 1.0f) { uu = 1.0f - uu; vv = 1.0f - vv; }
    float w0 = 1.0f - uu - vv;
    int f = p / NSAMP;
    int i0 = faces[3*f], i1 = faces[3*f+1], i2 = faces[3*f+2];
    px = verts[3*i0+0]*w0 + verts[3*i1+0]*uu + verts[3*i2+0]*vv;
    py = verts[3*i0+1]*w0 + verts[3*i1+1]*uu + verts[3*i2+1]*vv;
    pz = verts[3*i0+2]*w0 + verts[3*i1+2]*uu + verts[3*i2+2]*vv;
}

// ---- K_A: centroids + histograms (faces and points) ----
__global__ __launch_bounds__(256) void setup_hist(
    const float* __restrict__ verts, const int* __restrict__ faces,
    const float* __restrict__ uarr, const float* __restrict__ varr,
    float4* __restrict__ ctmp, unsigned* __restrict__ fcnt, unsigned* __restrict__ pcnt,
    int F, int N)
{
    int tid = blockIdx.x * blockDim.x + threadIdx.x;
    if (tid < F) {
        int i0 = faces[3*tid], i1 = faces[3*tid+1], i2 = faces[3*tid+2];
        float cx = (verts[3*i0+0] + verts[3*i1+0] + verts[3*i2+0]) * (1.0f/3.0f);
        float cy = (verts[3*i0+1] + verts[3*i1+1] + verts[3*i2+1]) * (1.0f/3.0f);
        float cz = (verts[3*i0+2] + verts[3*i1+2] + verts[3*i2+2]) * (1.0f/3.0f);
        float h  = fmaf(cx, cx, fmaf(cy, cy, cz*cz));
        ctmp[tid] = make_float4(cx, cy, cz, h);
        int b = (((binCoord(cx)<<4) | binCoord(cy))<<4) | binCoord(cz);
        atomicAdd(&fcnt[b], 1u);
    }
    if (tid < N) {
        float px, py, pz; computeP(tid, verts, faces, uarr, varr, px, py, pz);
        int b = (((binCoord(px)<<4) | binCoord(py))<<4) | binCoord(pz);
        atomicAdd(&pcnt[b], 1u);
    }
}

// ---- K_B: two 4096-bin exclusive prefix sums (one block) ----
__global__ __launch_bounds__(1024) void setup_prefix(
    const unsigned* __restrict__ fcnt, const unsigned* __restrict__ pcnt,
    unsigned* __restrict__ bstart, unsigned* __restrict__ fcur, unsigned* __restrict__ pcur)
{
    __shared__ unsigned part[1024];
    int t = threadIdx.x, base = t * 4;
    unsigned v0[4], s = 0;
    #pragma unroll
    for (int j = 0; j < 4; ++j) { v0[j] = fcnt[base+j]; s += v0[j]; }
    part[t] = s; __syncthreads();
    for (int off = 1; off < 1024; off <<= 1) {
        unsigned x = 0; if (t >= off) x = part[t-off];
        __syncthreads(); part[t] += x; __syncthreads();
    }
    unsigned ex = part[t] - s;
    #pragma unroll
    for (int j = 0; j < 4; ++j) { bstart[base+j] = ex; fcur[base+j] = ex; ex += v0[j]; }
    if (t == 1023) bstart[NBINS] = ex;
    __syncthreads();
    s = 0;
    #pragma unroll
    for (int j = 0; j < 4; ++j) { v0[j] = pcnt[base+j]; s += v0[j]; }
    part[t] = s; __syncthreads();
    for (int off = 1; off < 1024; off <<= 1) {
        unsigned x = 0; if (t >= off) x = part[t-off];
        __syncthreads(); part[t] += x; __syncthreads();
    }
    ex = part[t] - s;
    #pragma unroll
    for (int j = 0; j < 4; ++j) { pcur[base+j] = ex; ex += v0[j]; }
}

// ---- K_C: scatter faces and points into bin order ----
__global__ __launch_bounds__(256) void setup_scatter(
    const float* __restrict__ verts, const int* __restrict__ faces,
    const float* __restrict__ uarr, const float* __restrict__ varr,
    const float4* __restrict__ ctmp, unsigned* __restrict__ fcur, unsigned* __restrict__ pcur,
    float4* __restrict__ scent, unsigned* __restrict__ sidx, unsigned* __restrict__ perm,
    int F, int N)
{
    int tid = blockIdx.x * blockDim.x + threadIdx.x;
    if (tid < F) {
        float4 c = ctmp[tid];
        int b = (((binCoord(c.x)<<4) | binCoord(c.y))<<4) | binCoord(c.z);
        unsigned pos = atomicAdd(&fcur[b], 1u);
        scent[pos] = c; sidx[pos] = (unsigned)tid;
    }
    if (tid < N) {
        float px, py, pz; computeP(tid, verts, faces, uarr, varr, px, py, pz);
        int b = (((binCoord(px)<<4) | binCoord(py))<<4) | binCoord(pz);
        unsigned pos = atomicAdd(&pcur[b], 1u);
        perm[pos] = (unsigned)tid;
    }
}

// ---- K_D: per-bin bounding spheres ----
__global__ __launch_bounds__(256) void setup_spheres(
    const float4* __restrict__ scent, const unsigned* __restrict__ bstart,
    float4* __restrict__ sph)
{
    int b = blockIdx.x * blockDim.x + threadIdx.x;
    if (b >= NBINS) return;
    unsigned s = bstart[b], e = bstart[b+1];
    if (s == e) { sph[b] = make_float4(0.f, 0.f, 0.f, 0.f); return; }
    float sx = 0.f, sy = 0.f, sz = 0.f;
    for (unsigned i = s; i < e; ++i) { float4 c = scent[i]; sx += c.x; sy += c.y; sz += c.z; }
    float inv = 1.0f / (float)(e - s);
    sx *= inv; sy *= inv; sz *= inv;
    float r2 = 0.f;
    for (unsigned i = s; i < e; ++i) {
        float4 c = scent[i];
        float dx = c.x - sx, dy = c.y - sy, dz = c.z - sz;
        r2 = fmaxf(r2, fmaf(dx, dx, fmaf(dy, dy, dz*dz)));
    }
    float R = sqrtf(r2) * 1.00002f + 1e-6f;   // conservative inflate
    sph[b] = make_float4(sx, sy, sz, R);
}

// ---- K_E: ring-expansion k-NN scan + area epilogue ----
__global__ __launch_bounds__(256) void scan_kernel(
    const float* __restrict__ verts, const int* __restrict__ faces,
    const float* __restrict__ uarr, const float* __restrict__ varr,
    const float4* __restrict__ scent, const unsigned* __restrict__ sidx,
    const unsigned* __restrict__ bstart, const float4* __restrict__ sph,
    const unsigned* __restrict__ perm, float* __restrict__ out, int N)
{
    const int lane = threadIdx.x & 63, w = threadIdx.x >> 6;
    const int g0 = (blockIdx.x * 4 + w) * 64;
    if (g0 >= N) return;
    const int g = g0 + lane;
    const bool valid = g < N;
    const int p = (int)perm[valid ? g : (N-1)];

    float px, py, pz; computeP(p, verts, faces, uarr, varr, px, py, pz);
    float qx = -2.f*px, qy = -2.f*py, qz = -2.f*pz;
    float pp = fmaf(px, px, fmaf(py, py, pz*pz));
    int ix = binCoord(px), iy = binCoord(py), iz = binCoord(pz);
    float ccx = GLO + (ix + 0.5f)*GH, ccy = GLO + (iy + 0.5f)*GH, ccz = GLO + (iz + 0.5f)*GH;
    float Dinf = fmaxf(fabsf(px-ccx), fmaxf(fabsf(py-ccy), fabsf(pz-ccz)));

    unsigned k0=~0u, k1=~0u, k2=~0u, k3=~0u, k4=~0u;
    float d4f = __uint_as_float(0x7F800000u), d4s = d4f;   // +inf until filled

    for (int rho = 0; rho < NB; ++rho) {
        if (rho > 0) {
            // all unvisited cells are Chebyshev >= rho+... (ring >= rho+1 after this
            // iteration starts) -> checked BEFORE ring rho: unvisited >= rho
            float lhs = ((float)rho - 0.5f)*GH - Dinf;
            int done = (lhs > 0.f) && (lhs*lhs > d4f);
            if (__all(done)) break;
        }
        for (int dx = -rho; dx <= rho; ++dx)
        for (int dy = -rho; dy <= rho; ++dy)
        for (int dz = -rho; dz <= rho; ++dz) {
            int a1 = dx < 0 ? -dx : dx, a2 = dy < 0 ? -dy : dy, a3 = dz < 0 ? -dz : dz;
            int ch = a1 > a2 ? a1 : a2; ch = ch > a3 ? ch : a3;
            if (ch != rho) continue;                       // shell cells only
            int jx = ix + dx, jy = iy + dy, jz = iz + dz;
            bool inb = ((unsigned)jx < (unsigned)NB) & ((unsigned)jy < (unsigned)NB) & ((unsigned)jz < (unsigned)NB);
            int b = inb ? ((((jx<<4)|jy)<<4)|jz) : 0;
            unsigned s0 = bstart[b];
            int cnt = (int)(bstart[b+1] - s0);
            float4 S = sph[b];
            float ddx = px - S.x, ddy = py - S.y, ddz = pz - S.z;
            float dc2 = fmaf(ddx, ddx, fmaf(ddy, ddy, ddz*ddz));
            float thr = d4s + S.w;
            int myN = (inb && (dc2 <= thr*thr)) ? cnt : 0;
            for (int t = 0; __any(t < myN); ++t) {
                if (t < myN) {
                    float4 c = scent[s0 + t];
                    unsigned oi = sidx[s0 + t];
                    float sc = fmaf(qx, c.x, fmaf(qy, c.y, fmaf(qz, c.z, c.w + pp)));
                    unsigned u = (__float_as_uint(sc) & KMASK) | oi;
                    unsigned n4 = med3u(k3, k4, u), n3 = med3u(k2, k3, u);
                    unsigned n2 = med3u(k1, k2, u), n1 = med3u(k0, k1, u);
                    k0 = umn(k0, u); k1 = n1; k2 = n2; k3 = n3; k4 = n4;
                }
            }
            unsigned d4u = k4 & KMASK;                     // conservative upper bound
            d4f = __uint_as_float(d4u == KMASK ? 0x7F800000u : d4u + 0x2000u);
            d4s = sqrtf(d4f);
        }
    }

    float psum = 0.0f;
    if (valid) {
        unsigned kk[KNN] = { k0, k1, k2, k3, k4 };
        #pragma unroll
        for (int k = 0; k < KNN; ++k) {
            int fj = (int)(kk[k] & 0x1FFFu);
            int a0 = faces[3*fj], b1 = faces[3*fj+1], c2 = faces[3*fj+2];
            float ax = verts[3*a0+0], ay = verts[3*a0+1], az = verts[3*a0+2];
            float bx = verts[3*b1+0], by = verts[3*b1+1], bz = verts[3*b1+2];
            float cx = verts[3*c2+0], cy = verts[3*c2+1], cz = verts[3*c2+2];
            float e1x = bx-ax, e1y = by-ay, e1z = bz-az;
            float e2x = cx-ax, e2y = cy-ay, e2z = cz-az;
            float nx = e1y*e2z - e1z*e2y;
            float ny = e1z*e2x - e1x*e2z;
            float nz = e1x*e2y - e1y*e2x;
            float area = 0.5f * sqrtf(nx*nx + ny*ny + nz*nz);
            float cbx = cx-bx, cby = cy-by, cbz = cz-bz;
            float pbx = px-bx, pby = py-by, pbz = pz-bz;
            float uc = (cby*pbz - cbz*pby)*nx + (cbz*pbx - cbx*pbz)*ny + (cbx*pby - cby*pbx)*nz;
            float acx = ax-cx, acy = ay-cy, acz = az-cz;
            float pcx = px-cx, pcy = py-cy, pcz = pz-cz;
            float vc = (acy*pcz - acz*pcy)*nx + (acz*pcx - acx*pcz)*ny + (acx*pcy - acy*pcx)*nz;
            float pax = px-ax, pay = py-ay, paz = pz-az;
            float wc = (e1y*paz - e1z*pay)*nx + (e1z*pax - e1x*paz)*ny + (e1x*pay - e1y*pax)*nz;
            if (fabsf(area) > FEPS && uc >= 0.0f && vc >= 0.0f && wc >= 0.0f)
                psum += area;
        }
    }
    #pragma unroll
    for (int off = 32; off > 0; off >>= 1)
        psum += __shfl_down(psum, off, 64);
    if (lane == 0) atomicAdd(out, psum);
}

extern "C" void kernel_launch(void* const* d_in, const int* in_sizes, int n_in,
                              void* d_out, int out_size, void* d_ws, size_t ws_size,
                              hipStream_t stream) {
    const float* verts = (const float*)d_in[0];
    const int*   faces = (const int*)d_in[1];
    const float* u     = (const float*)d_in[2];
    const float* v     = (const float*)d_in[3];
    float*       out   = (float*)d_out;
    char*        ws    = (char*)d_ws;

    float4*   scent  = (float4*)(ws + OFF_SCENT);
    float4*   ctmp   = (float4*)(ws + OFF_CTMP);
    float4*   sph    = (float4*)(ws + OFF_SPH);
    unsigned* sidx   = (unsigned*)(ws + OFF_SIDX);
    unsigned* bstart = (unsigned*)(ws + OFF_BSTART);
    unsigned* fcur   = (unsigned*)(ws + OFF_FCUR);
    unsigned* pcur   = (unsigned*)(ws + OFF_PCUR);
    unsigned* fcnt   = (unsigned*)(ws + OFF_FCNT);
    unsigned* pcnt   = (unsigned*)(ws + OFF_PCNT);
    unsigned* perm   = (unsigned*)(ws + OFF_PERM);

    int F = in_sizes[1] / 3;    // 6000
    int N = in_sizes[2];        // 60000

    hipMemsetAsync(d_out, 0, sizeof(float), stream);
    hipMemsetAsync(ws + OFF_FCNT, 0, 2 * NBINS * sizeof(unsigned), stream);  // fcnt+pcnt

    int blocksFN = (N + 255) / 256;   // covers both F and N
    setup_hist   <<<blocksFN, 256, 0, stream>>>(verts, faces, u, v, ctmp, fcnt, pcnt, F, N);
    setup_prefix <<<1, 1024, 0, stream>>>(fcnt, pcnt, bstart, fcur, pcur);
    setup_scatter<<<blocksFN, 256, 0, stream>>>(verts, faces, u, v, ctmp, fcur, pcur,
                                                scent, sidx, perm, F, N);
    setup_spheres<<<(NBINS + 255) / 256, 256, 0, stream>>>(scent, bstart, sph);
    int blocksScan = (N + 4*64 - 1) / (4*64);   // 235
    scan_kernel  <<<blocksScan, 256, 0, stream>>>(verts, faces, u, v, scent, sidx,
                                                  bstart, sph, perm, out, N);
}

// Round 12
// 964.834 us; speedup vs baseline: 5.3291x; 5.3291x over previous
//
#include <hip/hip_runtime.h>
#include <float.h>
#include <math.h>

#define KNN    5
#define FEPS   1e-6f
#define NSAMP  10
#define NB     16
#define NBINS  4096
#define GLO    -2.4f
#define GH     0.3f
#define GINVH  (1.0f/0.3f)
#define KMASK  0xFFFFE000u

// ---- workspace layout (bytes) ----
#define OFF_SCENT   0          // float4[6016]  sorted centroids (x,y,z,|C|^2)
#define OFF_CTMP    98304      // float4[6016]  unsorted centroids
#define OFF_SPH     196608     // float4[4096]  per-bin sphere (cx,cy,cz,R)
#define OFF_SIDX    262144     // u32[6016]     sorted -> original face idx
#define OFF_BSTART  286720     // u32[4097]     bin start offsets (faces)
#define OFF_FCUR    304128     // u32[4096]     face scatter cursor
#define OFF_PCUR    321536     // u32[4096]     point scatter cursor
#define OFF_FCNT    338944     // u32[4096]     face histogram   } adjacent:
#define OFF_PCNT    355328     // u32[4096]     point histogram  } one memset
#define OFF_PERM    372736     // u32[60032]    sorted -> original point idx

static __device__ __forceinline__ unsigned umn(unsigned a, unsigned b){ return __builtin_elementwise_min(a, b); }
static __device__ __forceinline__ int imn(int a, int b){ return a < b ? a : b; }
static __device__ __forceinline__ int imx(int a, int b){ return a > b ? a : b; }
static __device__ __forceinline__ unsigned med3u(unsigned a, unsigned b, unsigned c){
    unsigned r; asm("v_med3_u32 %0, %1, %2, %3" : "=v"(r) : "v"(a), "v"(b), "v"(c)); return r;
}
static __device__ __forceinline__ int binCoord(float x){
    int i = (int)floorf((x - GLO) * GINVH);
    return i < 0 ? 0 : (i > NB-1 ? NB-1 : i);
}
static __device__ __forceinline__ void computeP(int p, const float* __restrict__ verts,
    const int* __restrict__ faces, const float* __restrict__ uarr, const float* __restrict__ varr,
    float& px, float& py, float& pz)
{
    float uu = uarr[p], vv = varr[p];
    if (uu + vv > 1.0f) { uu = 1.0f - uu; vv = 1.0f - vv; }
    float w0 = 1.0f - uu - vv;
    int f = p / NSAMP;
    int i0 = faces[3*f], i1 = faces[3*f+1], i2 = faces[3*f+2];
    px = verts[3*i0+0]*w0 + verts[3*i1+0]*uu + verts[3*i2+0]*vv;
    py = verts[3*i0+1]*w0 + verts[3*i1+1]*uu + verts[3*i2+1]*vv;
    pz = verts[3*i0+2]*w0 + verts[3*i1+2]*uu + verts[3*i2+2]*vv;
}

// ---- K_A: centroids + histograms (faces and points) ----
__global__ __launch_bounds__(256) void setup_hist(
    const float* __restrict__ verts, const int* __restrict__ faces,
    const float* __restrict__ uarr, const float* __restrict__ varr,
    float4* __restrict__ ctmp, unsigned* __restrict__ fcnt, unsigned* __restrict__ pcnt,
    int F, int N)
{
    int tid = blockIdx.x * blockDim.x + threadIdx.x;
    if (tid < F) {
        int i0 = faces[3*tid], i1 = faces[3*tid+1], i2 = faces[3*tid+2];
        float cx = (verts[3*i0+0] + verts[3*i1+0] + verts[3*i2+0]) * (1.0f/3.0f);
        float cy = (verts[3*i0+1] + verts[3*i1+1] + verts[3*i2+1]) * (1.0f/3.0f);
        float cz = (verts[3*i0+2] + verts[3*i1+2] + verts[3*i2+2]) * (1.0f/3.0f);
        float h  = fmaf(cx, cx, fmaf(cy, cy, cz*cz));
        ctmp[tid] = make_float4(cx, cy, cz, h);
        int b = (((binCoord(cx)<<4) | binCoord(cy))<<4) | binCoord(cz);
        atomicAdd(&fcnt[b], 1u);
    }
    if (tid < N) {
        float px, py, pz; computeP(tid, verts, faces, uarr, varr, px, py, pz);
        int b = (((binCoord(px)<<4) | binCoord(py))<<4) | binCoord(pz);
        atomicAdd(&pcnt[b], 1u);
    }
}

// ---- K_B: two 4096-bin exclusive prefix sums (one block) ----
__global__ __launch_bounds__(1024) void setup_prefix(
    const unsigned* __restrict__ fcnt, const unsigned* __restrict__ pcnt,
    unsigned* __restrict__ bstart, unsigned* __restrict__ fcur, unsigned* __restrict__ pcur)
{
    __shared__ unsigned part[1024];
    int t = threadIdx.x, base = t * 4;
    unsigned v0[4], s = 0;
    #pragma unroll
    for (int j = 0; j < 4; ++j) { v0[j] = fcnt[base+j]; s += v0[j]; }
    part[t] = s; __syncthreads();
    for (int off = 1; off < 1024; off <<= 1) {
        unsigned x = 0; if (t >= off) x = part[t-off];
        __syncthreads(); part[t] += x; __syncthreads();
    }
    unsigned ex = part[t] - s;
    #pragma unroll
    for (int j = 0; j < 4; ++j) { bstart[base+j] = ex; fcur[base+j] = ex; ex += v0[j]; }
    if (t == 1023) bstart[NBINS] = ex;
    __syncthreads();
    s = 0;
    #pragma unroll
    for (int j = 0; j < 4; ++j) { v0[j] = pcnt[base+j]; s += v0[j]; }
    part[t] = s; __syncthreads();
    for (int off = 1; off < 1024; off <<= 1) {
        unsigned x = 0; if (t >= off) x = part[t-off];
        __syncthreads(); part[t] += x; __syncthreads();
    }
    ex = part[t] - s;
    #pragma unroll
    for (int j = 0; j < 4; ++j) { pcur[base+j] = ex; ex += v0[j]; }
}

// ---- K_C: scatter faces and points into bin order ----
__global__ __launch_bounds__(256) void setup_scatter(
    const float* __restrict__ verts, const int* __restrict__ faces,
    const float* __restrict__ uarr, const float* __restrict__ varr,
    const float4* __restrict__ ctmp, unsigned* __restrict__ fcur, unsigned* __restrict__ pcur,
    float4* __restrict__ scent, unsigned* __restrict__ sidx, unsigned* __restrict__ perm,
    int F, int N)
{
    int tid = blockIdx.x * blockDim.x + threadIdx.x;
    if (tid < F) {
        float4 c = ctmp[tid];
        int b = (((binCoord(c.x)<<4) | binCoord(c.y))<<4) | binCoord(c.z);
        unsigned pos = atomicAdd(&fcur[b], 1u);
        scent[pos] = c; sidx[pos] = (unsigned)tid;
    }
    if (tid < N) {
        float px, py, pz; computeP(tid, verts, faces, uarr, varr, px, py, pz);
        int b = (((binCoord(px)<<4) | binCoord(py))<<4) | binCoord(pz);
        unsigned pos = atomicAdd(&pcur[b], 1u);
        perm[pos] = (unsigned)tid;
    }
}

// ---- K_D: per-bin bounding spheres ----
__global__ __launch_bounds__(256) void setup_spheres(
    const float4* __restrict__ scent, const unsigned* __restrict__ bstart,
    float4* __restrict__ sph)
{
    int b = blockIdx.x * blockDim.x + threadIdx.x;
    if (b >= NBINS) return;
    unsigned s = bstart[b], e = bstart[b+1];
    if (s == e) { sph[b] = make_float4(0.f, 0.f, 0.f, 0.f); return; }
    float sx = 0.f, sy = 0.f, sz = 0.f;
    for (unsigned i = s; i < e; ++i) { float4 c = scent[i]; sx += c.x; sy += c.y; sz += c.z; }
    float inv = 1.0f / (float)(e - s);
    sx *= inv; sy *= inv; sz *= inv;
    float r2 = 0.f;
    for (unsigned i = s; i < e; ++i) {
        float4 c = scent[i];
        float dx = c.x - sx, dy = c.y - sy, dz = c.z - sz;
        r2 = fmaxf(r2, fmaf(dx, dx, fmaf(dy, dy, dz*dz)));
    }
    float R = sqrtf(r2) * 1.00002f + 1e-6f;   // conservative inflate
    sph[b] = make_float4(sx, sy, sz, R);
}

// ---- K_E: WAVE-UNIFORM box-ring k-NN scan + area epilogue ----
__global__ __launch_bounds__(256) void scan_kernel(
    const float* __restrict__ verts, const int* __restrict__ faces,
    const float* __restrict__ uarr, const float* __restrict__ varr,
    const float4* __restrict__ scent, const unsigned* __restrict__ sidx,
    const unsigned* __restrict__ bstart, const float4* __restrict__ sph,
    const unsigned* __restrict__ perm, float* __restrict__ out, int N)
{
    const int lane = threadIdx.x & 63, w = threadIdx.x >> 6;
    const int g0 = (blockIdx.x * 4 + w) * 64;
    if (g0 >= N) return;
    const int g = g0 + lane;
    const bool valid = g < N;
    const int p = (int)perm[valid ? g : (N-1)];

    float px, py, pz; computeP(p, verts, faces, uarr, varr, px, py, pz);
    float qx = -2.f*px, qy = -2.f*py, qz = -2.f*pz;
    float pp = fmaf(px, px, fmaf(py, py, pz*pz));
    int ix = binCoord(px), iy = binCoord(py), iz = binCoord(pz);

    // ---- wave bounding box of cells (points are bin-sorted -> tiny box) ----
    int bx0 = ix, bx1 = ix, by0 = iy, by1 = iy, bz0 = iz, bz1 = iz;
    #pragma unroll
    for (int off = 32; off > 0; off >>= 1) {
        bx0 = imn(bx0, __shfl_xor(bx0, off, 64)); bx1 = imx(bx1, __shfl_xor(bx1, off, 64));
        by0 = imn(by0, __shfl_xor(by0, off, 64)); by1 = imx(by1, __shfl_xor(by1, off, 64));
        bz0 = imn(bz0, __shfl_xor(bz0, off, 64)); bz1 = imx(bz1, __shfl_xor(bz1, off, 64));
    }
    bx0 = __builtin_amdgcn_readfirstlane(bx0); bx1 = __builtin_amdgcn_readfirstlane(bx1);
    by0 = __builtin_amdgcn_readfirstlane(by0); by1 = __builtin_amdgcn_readfirstlane(by1);
    bz0 = __builtin_amdgcn_readfirstlane(bz0); bz1 = __builtin_amdgcn_readfirstlane(bz1);

    unsigned k0=~0u, k1=~0u, k2=~0u, k3=~0u, k4=~0u;
    float d4f = __uint_as_float(0x7F800000u);   // conservative upper bound of 5th key
    float d4s = d4f;

    for (int rho = 0; rho < 64; ++rho) {
        if (rho > 0) {
            // unvisited cells are >= (rho-1)*GH away from every lane's point
            float lhs = (float)(rho - 1) * GH;
            if (__all(lhs*lhs > d4f)) break;
            // expanded box already covered the full grid last ring -> nothing new
            if (bx0-(rho-1) <= 0 && bx1+(rho-1) >= NB-1 &&
                by0-(rho-1) <= 0 && by1+(rho-1) >= NB-1 &&
                bz0-(rho-1) <= 0 && bz1+(rho-1) >= NB-1) break;
        }
        int xlo = imx(bx0-rho, 0), xhi = imn(bx1+rho, NB-1);
        int ylo = imx(by0-rho, 0), yhi = imn(by1+rho, NB-1);
        int zlo = imx(bz0-rho, 0), zhi = imn(bz1+rho, NB-1);
        for (int jx = xlo; jx <= xhi; ++jx)
        for (int jy = ylo; jy <= yhi; ++jy)
        for (int jz = zlo; jz <= zhi; ++jz) {
            int cxd = imx(imx(bx0-jx, jx-bx1), 0);
            int cyd = imx(imx(by0-jy, jy-by1), 0);
            int czd = imx(imx(bz0-jz, jz-bz1), 0);
            int ch  = imx(cxd, imx(cyd, czd));
            if (ch != rho) continue;                 // shell-of-box cells only
            int b = (((jx<<4)|jy)<<4)|jz;            // wave-uniform
            unsigned s0 = bstart[b];
            int cnt = (int)(bstart[b+1] - s0);
            if (cnt == 0) continue;
            float4 S = sph[b];                       // uniform -> s_load
            float ddx = px - S.x, ddy = py - S.y, ddz = pz - S.z;
            float dc2 = fmaf(ddx, ddx, fmaf(ddy, ddy, ddz*ddz));
            float thr = d4s + S.w;
            if (!__any(dc2 <= thr*thr)) continue;    // no lane can improve from this cell
            for (int t = 0; t < cnt; ++t) {          // uniform trip count
                float4 c = scent[s0 + t];            // uniform -> broadcast
                unsigned oi = sidx[s0 + t];
                float sc = fmaf(qx, c.x, fmaf(qy, c.y, fmaf(qz, c.z, c.w + pp)));
                unsigned u = (__float_as_uint(sc) & KMASK) | oi;
                unsigned n4 = med3u(k3, k4, u), n3 = med3u(k2, k3, u);
                unsigned n2 = med3u(k1, k2, u), n1 = med3u(k0, k1, u);
                k0 = umn(k0, u); k1 = n1; k2 = n2; k3 = n3; k4 = n4;
            }
            unsigned d4u = k4 & KMASK;               // truncated -> round up one step
            d4f = __uint_as_float(d4u == KMASK ? 0x7F800000u : d4u + 0x2000u);
            d4s = sqrtf(d4f);
        }
    }

    float psum = 0.0f;
    if (valid) {
        unsigned kk[KNN] = { k0, k1, k2, k3, k4 };
        #pragma unroll
        for (int k = 0; k < KNN; ++k) {
            int fj = (int)(kk[k] & 0x1FFFu);
            int a0 = faces[3*fj], b1 = faces[3*fj+1], c2 = faces[3*fj+2];
            float ax = verts[3*a0+0], ay = verts[3*a0+1], az = verts[3*a0+2];
            float bx = verts[3*b1+0], by = verts[3*b1+1], bz = verts[3*b1+2];
            float cx = verts[3*c2+0], cy = verts[3*c2+1], cz = verts[3*c2+2];
            float e1x = bx-ax, e1y = by-ay, e1z = bz-az;
            float e2x = cx-ax, e2y = cy-ay, e2z = cz-az;
            float nx = e1y*e2z - e1z*e2y;
            float ny = e1z*e2x - e1x*e2z;
            float nz = e1x*e2y - e1y*e2x;
            float area = 0.5f * sqrtf(nx*nx + ny*ny + nz*nz);
            float cbx = cx-bx, cby = cy-by, cbz = cz-bz;
            float pbx = px-bx, pby = py-by, pbz = pz-bz;
            float uc = (cby*pbz - cbz*pby)*nx + (cbz*pbx - cbx*pbz)*ny + (cbx*pby - cby*pbx)*nz;
            float acx = ax-cx, acy = ay-cy, acz = az-cz;
            float pcx = px-cx, pcy = py-cy, pcz = pz-cz;
            float vc = (acy*pcz - acz*pcy)*nx + (acz*pcx - acx*pcz)*ny + (acx*pcy - acy*pcx)*nz;
            float pax = px-ax, pay = py-ay, paz = pz-az;
            float wc = (e1y*paz - e1z*pay)*nx + (e1z*pax - e1x*paz)*ny + (e1x*pay - e1y*pax)*nz;
            if (fabsf(area) > FEPS && uc >= 0.0f && vc >= 0.0f && wc >= 0.0f)
                psum += area;
        }
    }
    #pragma unroll
    for (int off = 32; off > 0; off >>= 1)
        psum += __shfl_down(psum, off, 64);
    if (lane == 0) atomicAdd(out, psum);
}

extern "C" void kernel_launch(void* const* d_in, const int* in_sizes, int n_in,
                              void* d_out, int out_size, void* d_ws, size_t ws_size,
                              hipStream_t stream) {
    const float* verts = (const float*)d_in[0];
    const int*   faces = (const int*)d_in[1];
    const float* u     = (const float*)d_in[2];
    const float* v     = (const float*)d_in[3];
    float*       out   = (float*)d_out;
    char*        ws    = (char*)d_ws;

    float4*   scent  = (float4*)(ws + OFF_SCENT);
    float4*   ctmp   = (float4*)(ws + OFF_CTMP);
    float4*   sph    = (float4*)(ws + OFF_SPH);
    unsigned* sidx   = (unsigned*)(ws + OFF_SIDX);
    unsigned* bstart = (unsigned*)(ws + OFF_BSTART);
    unsigned* fcur   = (unsigned*)(ws + OFF_FCUR);
    unsigned* pcur   = (unsigned*)(ws + OFF_PCUR);
    unsigned* fcnt   = (unsigned*)(ws + OFF_FCNT);
    unsigned* pcnt   = (unsigned*)(ws + OFF_PCNT);
    unsigned* perm   = (unsigned*)(ws + OFF_PERM);

    int F = in_sizes[1] / 3;    // 6000
    int N = in_sizes[2];        // 60000

    hipMemsetAsync(d_out, 0, sizeof(float), stream);
    hipMemsetAsync(ws + OFF_FCNT, 0, 2 * NBINS * sizeof(unsigned), stream);  // fcnt+pcnt

    int blocksFN = (N + 255) / 256;   // covers both F and N
    setup_hist   <<<blocksFN, 256, 0, stream>>>(verts, faces, u, v, ctmp, fcnt, pcnt, F, N);
    setup_prefix <<<1, 1024, 0, stream>>>(fcnt, pcnt, bstart, fcur, pcur);
    setup_scatter<<<blocksFN, 256, 0, stream>>>(verts, faces, u, v, ctmp, fcur, pcur,
                                                scent, sidx, perm, F, N);
    setup_spheres<<<(NBINS + 255) / 256, 256, 0, stream>>>(scent, bstart, sph);
    int blocksScan = (N + 4*64 - 1) / (4*64);   // 235
    scan_kernel  <<<blocksScan, 256, 0, stream>>>(verts, faces, u, v, scent, sidx,
                                                  bstart, sph, perm, out, N);
}

// Round 14
// 123.116 us; speedup vs baseline: 41.7633x; 7.8368x over previous
//
#include <hip/hip_runtime.h>
#include <float.h>

#define KNN   5
#define FEPS  1e-6f
#define NSAMP 10
#define NWAVE 8     // waves per block == centroid chunks
#define PPB   64    // points per block (lane == point)

// SoA centroid arrays inside d_ws (64B-aligned stride of 6144 floats)
#define CSTRIDE 6144
#define OFF_X   0
#define OFF_Y   (CSTRIDE*4)
#define OFF_Z   (CSTRIDE*8)
#define OFF_W   (CSTRIDE*12)

typedef __attribute__((ext_vector_type(2))) float f32x2;

static __device__ __forceinline__ unsigned umn(unsigned a, unsigned b){ return __builtin_elementwise_min(a, b); }
static __device__ __forceinline__ unsigned umx(unsigned a, unsigned b){ return __builtin_elementwise_max(a, b); }
// v_med3_u32: median of 3 — single VOP3, no builtin exposed, use asm.
static __device__ __forceinline__ unsigned med3u(unsigned a, unsigned b, unsigned c){
    unsigned r; asm("v_med3_u32 %0, %1, %2, %3" : "=v"(r) : "v"(a), "v"(b), "v"(c)); return r;
}

__global__ __launch_bounds__(256) void centroid_kernel(
    const float* __restrict__ verts, const int* __restrict__ faces,
    float* __restrict__ X, float* __restrict__ Y, float* __restrict__ Z,
    float* __restrict__ W, int F, int Fpad)
{
    int i = blockIdx.x * blockDim.x + threadIdx.x;
    if (i < F) {
        int i0 = faces[3*i], i1 = faces[3*i+1], i2 = faces[3*i+2];
        float cx = (verts[3*i0+0] + verts[3*i1+0] + verts[3*i2+0]) * (1.0f/3.0f);
        float cy = (verts[3*i0+1] + verts[3*i1+1] + verts[3*i2+1]) * (1.0f/3.0f);
        float cz = (verts[3*i0+2] + verts[3*i1+2] + verts[3*i2+2]) * (1.0f/3.0f);
        float h  = fmaf(cx, cx, fmaf(cy, cy, cz*cz));   // |C|^2
        X[i] = cx; Y[i] = cy; Z[i] = cz; W[i] = h;
    } else if (i < Fpad) {
        X[i] = 0.0f; Y[i] = 0.0f; Z[i] = 0.0f; W[i] = 3.0e38f;  // sentinel: never selected
    }
}

__global__ __launch_bounds__(512, 8) void scan_kernel(
    const float* __restrict__ verts, const int* __restrict__ faces,
    const float* __restrict__ uarr, const float* __restrict__ varr,
    const float* __restrict__ X, const float* __restrict__ Y,
    const float* __restrict__ Z, const float* __restrict__ W,
    float* __restrict__ out, int CH, int N)
{
    __shared__ unsigned cand[KNN][NWAVE][64];   // 4B lane stride = 2-way = free
    __shared__ float wsum[NWAVE];

    const int  lane  = threadIdx.x & 63;
    const int  w     = threadIdx.x >> 6;
    const int  p     = blockIdx.x * PPB + lane;
    const bool valid = p < N;
    const int  pc    = valid ? p : N - 1;       // clamp for safe loads

    // ---- this lane's sample point P (redundant across waves, cheap) ----
    float uu = uarr[pc], vv = varr[pc];
    if (uu + vv > 1.0f) { uu = 1.0f - uu; vv = 1.0f - vv; }
    float w0 = 1.0f - uu - vv;
    int  f  = pc / NSAMP;
    int  i0 = faces[3*f], i1 = faces[3*f+1], i2 = faces[3*f+2];
    float px = verts[3*i0+0]*w0 + verts[3*i1+0]*uu + verts[3*i2+0]*vv;
    float py = verts[3*i0+1]*w0 + verts[3*i1+1]*uu + verts[3*i2+1]*vv;
    float pz = verts[3*i0+2]*w0 + verts[3*i1+2]*uu + verts[3*i2+2]*vv;
    float qx = -2.0f*px, qy = -2.0f*py, qz = -2.0f*pz;
    float pp = fmaf(px, px, fmaf(py, py, pz*pz));      // |P|^2

    // broadcast pairs for packed math
    f32x2 qx2 = {qx, qx}, qy2 = {qy, qy}, qz2 = {qz, qz}, pp2 = {pp, pp};

    // ---- wave-uniform centroid chunk of size CH (multiple of 8) ----
    const int c0 = __builtin_amdgcn_readfirstlane(CH * w);
    const float* __restrict__ Xw = X + c0;
    const float* __restrict__ Yw = Y + c0;
    const float* __restrict__ Zw = Z + c0;
    const float* __restrict__ Ww = W + c0;

    // keep the key-pack mask in a VGPR so v_bfi_b32 can take the SGPR index
    unsigned maskv;
    asm("v_mov_b32 %0, 0xFFFFE000" : "=v"(maskv));

    // packed key: [31:13] = high float bits of d^2 (>=0, so bit order == value),
    //             [12:0]  = global centroid index -> u32 compare == lex (d2, idx)
    unsigned k0=0xFFFFFFFFu,k1=0xFFFFFFFFu,k2=0xFFFFFFFFu,k3=0xFFFFFFFFu,k4=0xFFFFFFFFu;

    #pragma unroll 4
    for (int t = 0; t < CH; t += 2) {
        // wave-uniform SoA pair loads -> s_load_dwordx2 (even-aligned: c0, t even)
        unsigned long long X2 = *(const unsigned long long*)(Xw + t);
        unsigned long long Y2 = *(const unsigned long long*)(Yw + t);
        unsigned long long Z2 = *(const unsigned long long*)(Zw + t);
        unsigned long long W2 = *(const unsigned long long*)(Ww + t);
        // packed distance, bit-identical to: fmaf(qx,x,fmaf(qy,y,fmaf(qz,z,w+pp)))
        f32x2 acc;
        asm("v_pk_add_f32 %0, %1, %2"     : "=v"(acc) : "s"(W2), "v"(pp2));
        asm("v_pk_fma_f32 %0, %1, %2, %3" : "=v"(acc) : "v"(qz2), "s"(Z2), "v"(acc));
        asm("v_pk_fma_f32 %0, %1, %2, %3" : "=v"(acc) : "v"(qy2), "s"(Y2), "v"(acc));
        asm("v_pk_fma_f32 %0, %1, %2, %3" : "=v"(acc) : "v"(qx2), "s"(X2), "v"(acc));
        unsigned ua, ub;
        asm("v_bfi_b32 %0, %1, %2, %3" : "=v"(ua)
            : "v"(maskv), "v"(__float_as_uint(acc[0])), "s"(c0 + t));
        asm("v_bfi_b32 %0, %1, %2, %3" : "=v"(ub)
            : "v"(maskv), "v"(__float_as_uint(acc[1])), "s"(c0 + t + 1));
        unsigned wm = umn(ua, ub);
        unsigned lm = umx(ua, ub);
        // insert the pair-min (5 ops)
        {
            unsigned n4 = med3u(k3, k4, wm);
            unsigned n3 = med3u(k2, k3, wm);
            unsigned n2 = med3u(k1, k2, wm);
            unsigned n1 = med3u(k0, k1, wm);
            k0 = umn(k0, wm); k1 = n1; k2 = n2; k3 = n3; k4 = n4;
        }
        // pair-max only matters if it would displace k4 for some lane.
        // Inserting an oversized key is an identity on the sorted list, so
        // no lane masking is needed -> exact same result as sequential.
        if (__any(lm < k4)) {
            unsigned n4 = med3u(k3, k4, lm);
            unsigned n3 = med3u(k2, k3, lm);
            unsigned n2 = med3u(k1, k2, lm);
            unsigned n1 = med3u(k0, k1, lm);
            k0 = umn(k0, lm); k1 = n1; k2 = n2; k3 = n3; k4 = n4;
        }
    }

    cand[0][w][lane] = k0;
    cand[1][w][lane] = k1;
    cand[2][w][lane] = k2;
    cand[3][w][lane] = k3;
    cand[4][w][lane] = k4;
    __syncthreads();

    // ---- merge the 8 partial sorted top-5 lists (only waves 0..4) ----
    float psum = 0.0f;
    if (valid && w < KNN) {
        unsigned m0=0xFFFFFFFFu,m1=0xFFFFFFFFu,m2=0xFFFFFFFFu,m3=0xFFFFFFFFu,m4=0xFFFFFFFFu;
        for (int cw2 = 0; cw2 < NWAVE; ++cw2) {
            #pragma unroll
            for (int k = 0; k < KNN; ++k) {
                unsigned u = cand[k][cw2][lane];
                unsigned n4 = med3u(m3, m4, u);
                unsigned n3 = med3u(m2, m3, u);
                unsigned n2 = med3u(m1, m2, u);
                unsigned n1 = med3u(m0, m1, u);
                m0 = umn(m0, u); m1 = n1; m2 = n2; m3 = n3; m4 = n4;
            }
        }
        // wave w tests slot w's triangle for its lane's point
        unsigned mw = (w == 0) ? m0 : (w == 1) ? m1 : (w == 2) ? m2 : (w == 3) ? m3 : m4;
        int fj = (int)(mw & 0x1FFFu);

        int a0 = faces[3*fj], a1 = faces[3*fj+1], a2 = faces[3*fj+2];
        float ax = verts[3*a0+0], ay = verts[3*a0+1], az = verts[3*a0+2];
        float bx = verts[3*a1+0], by = verts[3*a1+1], bz = verts[3*a1+2];
        float cx = verts[3*a2+0], cy = verts[3*a2+1], cz = verts[3*a2+2];

        float e1x = bx-ax, e1y = by-ay, e1z = bz-az;   // b-a
        float e2x = cx-ax, e2y = cy-ay, e2z = cz-az;   // c-a
        float nx = e1y*e2z - e1z*e2y;
        float ny = e1z*e2x - e1x*e2z;
        float nz = e1x*e2y - e1y*e2x;
        float area = 0.5f * sqrtf(nx*nx + ny*ny + nz*nz);

        float cbx = cx-bx, cby = cy-by, cbz = cz-bz;
        float pbx = px-bx, pby = py-by, pbz = pz-bz;
        float uc = (cby*pbz - cbz*pby)*nx + (cbz*pbx - cbx*pbz)*ny + (cbx*pby - cby*pbx)*nz;

        float acx = ax-cx, acy = ay-cy, acz = az-cz;
        float pcx = px-cx, pcy = py-cy, pcz = pz-cz;
        float vc = (acy*pcz - acz*pcy)*nx + (acz*pcx - acx*pcz)*ny + (acx*pcy - acy*pcx)*nz;

        float pax = px-ax, pay = py-ay, paz = pz-az;
        float wc = (e1y*paz - e1z*pay)*nx + (e1z*pax - e1x*paz)*ny + (e1x*pay - e1y*pax)*nz;

        if (fabsf(area) > FEPS && uc >= 0.0f && vc >= 0.0f && wc >= 0.0f)
            psum = area;
    }

    // ---- reduce: 64-wide shuffle, across 8 waves, one atomic/block ----
    #pragma unroll
    for (int off = 32; off > 0; off >>= 1)
        psum += __shfl_down(psum, off, 64);
    if (lane == 0) wsum[w] = psum;
    __syncthreads();
    if (threadIdx.x == 0) {
        float t = 0.0f;
        #pragma unroll
        for (int i = 0; i < NWAVE; ++i) t += wsum[i];
        atomicAdd(out, t);
    }
}

extern "C" void kernel_launch(void* const* d_in, const int* in_sizes, int n_in,
                              void* d_out, int out_size, void* d_ws, size_t ws_size,
                              hipStream_t stream) {
    const float* verts = (const float*)d_in[0];
    const int*   faces = (const int*)d_in[1];
    const float* u     = (const float*)d_in[2];
    const float* v     = (const float*)d_in[3];
    float*       out   = (float*)d_out;
    char*        ws    = (char*)d_ws;

    float* X = (float*)(ws + OFF_X);
    float* Y = (float*)(ws + OFF_Y);
    float* Z = (float*)(ws + OFF_Z);
    float* W = (float*)(ws + OFF_W);

    int F = in_sizes[1] / 3;    // 6000
    int N = in_sizes[2];        // 60000
    int Fpad = ((F + NWAVE*8 - 1) / (NWAVE*8)) * (NWAVE*8);   // 6016 -> chunk 752 = 8*94
    int CH   = Fpad / NWAVE;

    hipMemsetAsync(d_out, 0, sizeof(float), stream);   // atomic accumulator
    centroid_kernel<<<(Fpad + 255) / 256, 256, 0, stream>>>(verts, faces, X, Y, Z, W, F, Fpad);
    int blocks = (N + PPB - 1) / PPB;                  // 938
    scan_kernel<<<blocks, 512, 0, stream>>>(verts, faces, u, v, X, Y, Z, W, out, CH, N);
}

// Round 15
// 104.548 us; speedup vs baseline: 49.1804x; 1.1776x over previous
//
#include <hip/hip_runtime.h>
#include <float.h>

#define KNN   5
#define FEPS  1e-6f
#define NSAMP 10
#define NWAVE 8     // waves per block == centroid chunks
#define PPB   64    // points per block (lane == point)

static __device__ __forceinline__ unsigned umn(unsigned a, unsigned b){ return __builtin_elementwise_min(a, b); }
static __device__ __forceinline__ unsigned umx(unsigned a, unsigned b){ return __builtin_elementwise_max(a, b); }
// v_med3_u32: median of 3 — single VOP3, no builtin exposed, use asm.
static __device__ __forceinline__ unsigned med3u(unsigned a, unsigned b, unsigned c){
    unsigned r; asm("v_med3_u32 %0, %1, %2, %3" : "=v"(r) : "v"(a), "v"(b), "v"(c)); return r;
}

__global__ __launch_bounds__(256) void centroid_kernel(
    const float* __restrict__ verts, const int* __restrict__ faces,
    float4* __restrict__ cent, int F, int Fpad)
{
    int i = blockIdx.x * blockDim.x + threadIdx.x;
    if (i < F) {
        int i0 = faces[3*i], i1 = faces[3*i+1], i2 = faces[3*i+2];
        float cx = (verts[3*i0+0] + verts[3*i1+0] + verts[3*i2+0]) * (1.0f/3.0f);
        float cy = (verts[3*i0+1] + verts[3*i1+1] + verts[3*i2+1]) * (1.0f/3.0f);
        float cz = (verts[3*i0+2] + verts[3*i1+2] + verts[3*i2+2]) * (1.0f/3.0f);
        float h  = fmaf(cx, cx, fmaf(cy, cy, cz*cz));   // |C|^2
        cent[i] = make_float4(cx, cy, cz, h);
    } else if (i < Fpad) {
        cent[i] = make_float4(0.0f, 0.0f, 0.0f, 3.0e38f);  // sentinel: never selected
    }
}

__global__ __launch_bounds__(512, 8) void scan_kernel(
    const float* __restrict__ verts, const int* __restrict__ faces,
    const float* __restrict__ uarr, const float* __restrict__ varr,
    const float4* __restrict__ cent,
    float* __restrict__ out, int CH, int N)
{
    __shared__ unsigned cand[KNN][NWAVE][64];   // 4B lane stride = 2-way = free
    __shared__ float wsum[NWAVE];

    const int  lane  = threadIdx.x & 63;
    const int  w     = threadIdx.x >> 6;
    const int  p     = blockIdx.x * PPB + lane;
    const bool valid = p < N;
    const int  pc    = valid ? p : N - 1;       // clamp for safe loads

    // ---- this lane's sample point P (redundant across waves, cheap) ----
    float uu = uarr[pc], vv = varr[pc];
    if (uu + vv > 1.0f) { uu = 1.0f - uu; vv = 1.0f - vv; }
    float w0 = 1.0f - uu - vv;
    int  f  = pc / NSAMP;
    int  i0 = faces[3*f], i1 = faces[3*f+1], i2 = faces[3*f+2];
    float px = verts[3*i0+0]*w0 + verts[3*i1+0]*uu + verts[3*i2+0]*vv;
    float py = verts[3*i0+1]*w0 + verts[3*i1+1]*uu + verts[3*i2+1]*vv;
    float pz = verts[3*i0+2]*w0 + verts[3*i1+2]*uu + verts[3*i2+2]*vv;
    float qx = -2.0f*px, qy = -2.0f*py, qz = -2.0f*pz;
    float pp = fmaf(px, px, fmaf(py, py, pz*pz));      // |P|^2

    // ---- wave-uniform centroid chunk of size CH (multiple of 8) ----
    const int c0 = __builtin_amdgcn_readfirstlane(CH * w);
    const float4* __restrict__ cw = cent + c0;

    // keep the key-pack mask in a VGPR so v_bfi_b32 can take the SGPR index
    unsigned maskv;
    asm("v_mov_b32 %0, 0xFFFFE000" : "=v"(maskv));

    // packed key: [31:13] = high float bits of d^2 (>=0, so bit order == value),
    //             [12:0]  = global centroid index -> u32 compare == lex (d2, idx)
    unsigned k0=0xFFFFFFFFu,k1=0xFFFFFFFFu,k2=0xFFFFFFFFu,k3=0xFFFFFFFFu,k4=0xFFFFFFFFu;

    #pragma unroll 4
    for (int t = 0; t < CH; t += 2) {
        float4 ca = cw[t];                // wave-uniform -> s_load
        float4 cb = cw[t+1];
        float ha = ca.w + pp;             // |C|^2 + |P|^2
        float hb = cb.w + pp;
        float sa = fmaf(qx, ca.x, fmaf(qy, ca.y, fmaf(qz, ca.z, ha)));  // d^2 >= 0
        float sb = fmaf(qx, cb.x, fmaf(qy, cb.y, fmaf(qz, cb.z, hb)));
        unsigned ua, ub;
        asm("v_bfi_b32 %0, %1, %2, %3" : "=v"(ua)
            : "v"(maskv), "v"(__float_as_uint(sa)), "s"(c0 + t));
        asm("v_bfi_b32 %0, %1, %2, %3" : "=v"(ub)
            : "v"(maskv), "v"(__float_as_uint(sb)), "s"(c0 + t + 1));
        unsigned wm = umn(ua, ub);
        unsigned lm = umx(ua, ub);
        // insert the pair-min (5 ops)
        {
            unsigned n4 = med3u(k3, k4, wm);
            unsigned n3 = med3u(k2, k3, wm);
            unsigned n2 = med3u(k1, k2, wm);
            unsigned n1 = med3u(k0, k1, wm);
            k0 = umn(k0, wm); k1 = n1; k2 = n2; k3 = n3; k4 = n4;
        }
        // pair-max only matters if it would displace k4 for some lane.
        // Inserting an oversized key is an identity on the sorted list, so
        // no lane masking is needed -> exact same result as sequential.
        if (__any(lm < k4)) {
            unsigned n4 = med3u(k3, k4, lm);
            unsigned n3 = med3u(k2, k3, lm);
            unsigned n2 = med3u(k1, k2, lm);
            unsigned n1 = med3u(k0, k1, lm);
            k0 = umn(k0, lm); k1 = n1; k2 = n2; k3 = n3; k4 = n4;
        }
    }

    cand[0][w][lane] = k0;
    cand[1][w][lane] = k1;
    cand[2][w][lane] = k2;
    cand[3][w][lane] = k3;
    cand[4][w][lane] = k4;
    __syncthreads();

    // ---- merge the 8 partial sorted top-5 lists (only waves 0..4) ----
    float psum = 0.0f;
    if (valid && w < KNN) {
        unsigned m0=0xFFFFFFFFu,m1=0xFFFFFFFFu,m2=0xFFFFFFFFu,m3=0xFFFFFFFFu,m4=0xFFFFFFFFu;
        for (int cw2 = 0; cw2 < NWAVE; ++cw2) {
            #pragma unroll
            for (int k = 0; k < KNN; ++k) {
                unsigned u = cand[k][cw2][lane];
                unsigned n4 = med3u(m3, m4, u);
                unsigned n3 = med3u(m2, m3, u);
                unsigned n2 = med3u(m1, m2, u);
                unsigned n1 = med3u(m0, m1, u);
                m0 = umn(m0, u); m1 = n1; m2 = n2; m3 = n3; m4 = n4;
            }
        }
        // wave w tests slot w's triangle for its lane's point
        unsigned mw = (w == 0) ? m0 : (w == 1) ? m1 : (w == 2) ? m2 : (w == 3) ? m3 : m4;
        int fj = (int)(mw & 0x1FFFu);

        int a0 = faces[3*fj], a1 = faces[3*fj+1], a2 = faces[3*fj+2];
        float ax = verts[3*a0+0], ay = verts[3*a0+1], az = verts[3*a0+2];
        float bx = verts[3*a1+0], by = verts[3*a1+1], bz = verts[3*a1+2];
        float cx = verts[3*a2+0], cy = verts[3*a2+1], cz = verts[3*a2+2];

        float e1x = bx-ax, e1y = by-ay, e1z = bz-az;   // b-a
        float e2x = cx-ax, e2y = cy-ay, e2z = cz-az;   // c-a
        float nx = e1y*e2z - e1z*e2y;
        float ny = e1z*e2x - e1x*e2z;
        float nz = e1x*e2y - e1y*e2x;
        float area = 0.5f * sqrtf(nx*nx + ny*ny + nz*nz);

        float cbx = cx-bx, cby = cy-by, cbz = cz-bz;
        float pbx = px-bx, pby = py-by, pbz = pz-bz;
        float uc = (cby*pbz - cbz*pby)*nx + (cbz*pbx - cbx*pbz)*ny + (cbx*pby - cby*pbx)*nz;

        float acx = ax-cx, acy = ay-cy, acz = az-cz;
        float pcx = px-cx, pcy = py-cy, pcz = pz-cz;
        float vc = (acy*pcz - acz*pcy)*nx + (acz*pcx - acx*pcz)*ny + (acx*pcy - acy*pcx)*nz;

        float pax = px-ax, pay = py-ay, paz = pz-az;
        float wc = (e1y*paz - e1z*pay)*nx + (e1z*pax - e1x*paz)*ny + (e1x*pay - e1y*pax)*nz;

        if (fabsf(area) > FEPS && uc >= 0.0f && vc >= 0.0f && wc >= 0.0f)
            psum = area;
    }

    // ---- reduce: 64-wide shuffle, across 8 waves, one atomic/block ----
    #pragma unroll
    for (int off = 32; off > 0; off >>= 1)
        psum += __shfl_down(psum, off, 64);
    if (lane == 0) wsum[w] = psum;
    __syncthreads();
    if (threadIdx.x == 0) {
        float t = 0.0f;
        #pragma unroll
        for (int i = 0; i < NWAVE; ++i) t += wsum[i];
        atomicAdd(out, t);
    }
}

extern "C" void kernel_launch(void* const* d_in, const int* in_sizes, int n_in,
                              void* d_out, int out_size, void* d_ws, size_t ws_size,
                              hipStream_t stream) {
    const float* verts = (const float*)d_in[0];
    const int*   faces = (const int*)d_in[1];
    const float* u     = (const float*)d_in[2];
    const float* v     = (const float*)d_in[3];
    float*       out   = (float*)d_out;
    float4*      cent  = (float4*)d_ws;

    int F = in_sizes[1] / 3;    // 6000
    int N = in_sizes[2];        // 60000
    int Fpad = ((F + NWAVE*8 - 1) / (NWAVE*8)) * (NWAVE*8);   // 6016 -> chunk 752 = 8*94
    int CH   = Fpad / NWAVE;

    hipMemsetAsync(d_out, 0, sizeof(float), stream);   // atomic accumulator
    centroid_kernel<<<(Fpad + 255) / 256, 256, 0, stream>>>(verts, faces, cent, F, Fpad);
    int blocks = (N + PPB - 1) / PPB;                  // 938
    scan_kernel<<<blocks, 512, 0, stream>>>(verts, faces, u, v, cent, out, CH, N);
}